// Round 13
// baseline (316.887 us; speedup 1.0000x reference)
//
#include <hip/hip_runtime.h>

// out[b,c,y,x] = sum_{kdy,kdx in [0,9)} corr[b, kdy*9+kdx, y+4-kdy, x+4-kdx] * feat[b,c, y+4-kdy, x+4-kdx]
// MFMA formulation (R11 structure): per (b,y): out[C,X] = sum_kdy A_kdy[C,K] * M_kdy[K,X]
//   A[c][sxp] = feat[b,c,sy,sxp-4] (bf16, zero-padded cols 0-3 / 100-103), sy = y+4-kdy
//   M compact-banded (R12-validated): per 16-wide x-tile t, K-base kb = t<5 ? 16t : 72,
//   M_sh[x][sxp-kb(x)] = corr[b, kdy*9+(x+8-sxp), sy, sxp-4]; out-of-band entries zeroed once.
// R13: single-buf A + compact dbuf M -> 67KB LDS -> 2 blocks/CU; T14 half-prefetch; cvt_pk.

#define RR 4
#define DD 9
#define D2 81
#define Bn 16
#define Cn 256
#define Hn 96
#define Wn 96
#define HWn (Hn*Wn)
#define NTH 512
#define KW  104           // A row width (ushort); 208 B stride, 16B-aligned fragments
#define MW  36            // M compact window; 72 B stride -> conflict-free uint2 reads

typedef __attribute__((ext_vector_type(8))) short bf16x8;
typedef __attribute__((ext_vector_type(4))) float f32x4;

__device__ __forceinline__ uint cvt_pk(float lo, float hi) {   // 2xf32 -> packed bf16 (1 instr)
    uint r;
    asm("v_cvt_pk_bf16_f32 %0, %1, %2" : "=v"(r) : "v"(lo), "v"(hi));
    return r;
}
__device__ __forceinline__ ushort f2bf(float f) {              // scalar RNE fallback
    uint u = __float_as_uint(f);
    return (ushort)((u + 0x7FFFu + ((u >> 16) & 1u)) >> 16);
}

__global__ __launch_bounds__(NTH, 4)
void corrT13_kernel(const float* __restrict__ corr,
                    const float* __restrict__ feat,
                    float* __restrict__ out)
{
    __shared__ ushort A_sh[Cn][KW];        // 53248 B, single buffer
    __shared__ ushort M_sh[2][Wn][MW];     // 13824 B, double buffer

    // XCD-chunked dispatch: y contiguous per XCD (grid 1536 = 8*192)
    int bid = blockIdx.x;
    int L   = (bid & 7) * 192 + (bid >> 3);
    int y   = L % Hn;
    int b   = L / Hn;

    const int tid  = threadIdx.x;
    const int lane = tid & 63;
    const int wid  = tid >> 6;            // wave -> 32-channel strip
    const int mrow = lane & 15;
    const int kq   = lane >> 4;
    const int kgrp = kq << 3;             // K sub-base 0,8,16,24

    // ---- zero once: A pads + all of M (out-of-band slots stay 0 forever) ----
    for (int i = tid; i < Cn; i += NTH) {
        *reinterpret_cast<uint2*>(&A_sh[i][0])   = make_uint2(0u, 0u);   // cols 0..3
        *reinterpret_cast<uint2*>(&A_sh[i][100]) = make_uint2(0u, 0u);   // cols 100..103
    }
    for (int i = tid; i < (int)(sizeof(M_sh) / 4); i += NTH) ((uint*)M_sh)[i] = 0u;
    __syncthreads();

    const int klo = max(0, y - (Hn - 1 - RR));   // valid kdy: sy = y+4-kdy in [0,96)
    const int khi = min(DD - 1, y + RR);

    const int ac  = tid >> 1;            // A staging: 2 threads per channel row
    const int seg = tid & 1;             // 48-float half row
    const float* fbase = feat + (((size_t)b * Cn + ac) * Hn) * Wn + seg * 48;

    // ---- prologue: stage A + M for kdy = klo ----
    {
        const int sy = y + RR - klo;
        const float* src = fbase + (size_t)sy * Wn;
        #pragma unroll
        for (int i = 0; i < 12; ++i) {
            float4 v = *reinterpret_cast<const float4*>(src + i * 4);
            *reinterpret_cast<uint2*>(&A_sh[ac][4 + seg * 48 + i * 4])
                = make_uint2(cvt_pk(v.x, v.y), cvt_pk(v.z, v.w));
        }
        for (int t = tid; t < DD * Wn; t += NTH) {
            int kdx = t / Wn, x = t - kdx * Wn;
            int sxp = x + 2 * RR - kdx;
            int kbx = (x >= 80) ? 72 : (x & ~15);
            int sxc = min(max(sxp - RR, 0), Wn - 1);    // OOB value hits zeroed A pad
            M_sh[0][x][sxp - kbx] = f2bf(corr[((size_t)b * D2 + klo * DD + kdx) * HWn + sy * Wn + sxc]);
        }
    }
    __syncthreads();

    f32x4 acc[2][6];
    #pragma unroll
    for (int ct = 0; ct < 2; ++ct)
        #pragma unroll
        for (int t6 = 0; t6 < 6; ++t6)
            acc[ct][t6] = (f32x4){0.f, 0.f, 0.f, 0.f};

    #pragma unroll 1
    for (int kk = klo; kk <= khi; ++kk) {
        const int pb = (kk - klo) & 1;
        const bool vn = (kk + 1 <= khi);              // block-uniform
        const float* srcn = fbase + (size_t)(y + RR - (kk + 1)) * Wn;

        // -- T14 issue-early: half of next A row (24 VGPR) + next M scalars --
        float4 fv0, fv1, fv2, fv3, fv4, fv5;
        float mv0 = 0.f, mv1 = 0.f;
        if (vn) {
            fv0 = *reinterpret_cast<const float4*>(srcn);
            fv1 = *reinterpret_cast<const float4*>(srcn + 4);
            fv2 = *reinterpret_cast<const float4*>(srcn + 8);
            fv3 = *reinterpret_cast<const float4*>(srcn + 12);
            fv4 = *reinterpret_cast<const float4*>(srcn + 16);
            fv5 = *reinterpret_cast<const float4*>(srcn + 20);
            const int syn = y + RR - (kk + 1);
            {
                int t = tid, kdx = t / Wn, x = t - kdx * Wn;
                int sxc = min(max(x + RR - kdx, 0), Wn - 1);
                mv0 = corr[((size_t)b * D2 + (kk + 1) * DD + kdx) * HWn + syn * Wn + sxc];
            }
            if (tid + NTH < DD * Wn) {
                int t = tid + NTH, kdx = t / Wn, x = t - kdx * Wn;
                int sxc = min(max(x + RR - kdx, 0), Wn - 1);
                mv1 = corr[((size_t)b * D2 + (kk + 1) * DD + kdx) * HWn + syn * Wn + sxc];
            }
        }

        // -- MFMA phase: 12 x v_mfma_f32_16x16x32_bf16 per wave --
        #pragma unroll
        for (int t6 = 0; t6 < 6; ++t6) {
            const int kb = (t6 == 5) ? 72 : t6 * 16;
            const ushort* mp = &M_sh[pb][t6 * 16 + mrow][kgrp];
            uint2 m0 = *reinterpret_cast<const uint2*>(mp);
            uint2 m1 = *reinterpret_cast<const uint2*>(mp + 4);
            uint4 bw = make_uint4(m0.x, m0.y, m1.x, m1.y);
            bf16x8 bfr = *reinterpret_cast<bf16x8*>(&bw);
            #pragma unroll
            for (int ct = 0; ct < 2; ++ct) {
                bf16x8 afr = *reinterpret_cast<const bf16x8*>(&A_sh[wid * 32 + ct * 16 + mrow][kb + kgrp]);
                acc[ct][t6] = __builtin_amdgcn_mfma_f32_16x16x32_bf16(afr, bfr, acc[ct][t6], 0, 0, 0);
            }
        }
        __syncthreads();                               // all waves done reading A_sh

        // -- write-late: prefetched half1, then direct half2, then M --
        if (vn) {
            *reinterpret_cast<uint2*>(&A_sh[ac][4 + seg * 48 + 0])  = make_uint2(cvt_pk(fv0.x, fv0.y), cvt_pk(fv0.z, fv0.w));
            *reinterpret_cast<uint2*>(&A_sh[ac][4 + seg * 48 + 4])  = make_uint2(cvt_pk(fv1.x, fv1.y), cvt_pk(fv1.z, fv1.w));
            *reinterpret_cast<uint2*>(&A_sh[ac][4 + seg * 48 + 8])  = make_uint2(cvt_pk(fv2.x, fv2.y), cvt_pk(fv2.z, fv2.w));
            *reinterpret_cast<uint2*>(&A_sh[ac][4 + seg * 48 + 12]) = make_uint2(cvt_pk(fv3.x, fv3.y), cvt_pk(fv3.z, fv3.w));
            *reinterpret_cast<uint2*>(&A_sh[ac][4 + seg * 48 + 16]) = make_uint2(cvt_pk(fv4.x, fv4.y), cvt_pk(fv4.z, fv4.w));
            *reinterpret_cast<uint2*>(&A_sh[ac][4 + seg * 48 + 20]) = make_uint2(cvt_pk(fv5.x, fv5.y), cvt_pk(fv5.z, fv5.w));
            #pragma unroll
            for (int i = 6; i < 12; ++i) {
                float4 v = *reinterpret_cast<const float4*>(srcn + i * 4);
                *reinterpret_cast<uint2*>(&A_sh[ac][4 + seg * 48 + i * 4])
                    = make_uint2(cvt_pk(v.x, v.y), cvt_pk(v.z, v.w));
            }
            {
                int t = tid, kdx = t / Wn, x = t - kdx * Wn;
                int sxp = x + 2 * RR - kdx;
                int kbx = (x >= 80) ? 72 : (x & ~15);
                M_sh[pb ^ 1][x][sxp - kbx] = f2bf(mv0);
            }
            if (tid + NTH < DD * Wn) {
                int t = tid + NTH, kdx = t / Wn, x = t - kdx * Wn;
                int sxp = x + 2 * RR - kdx;
                int kbx = (x >= 80) ? 72 : (x & ~15);
                M_sh[pb ^ 1][x][sxp - kbx] = f2bf(mv1);
            }
        }
        __syncthreads();                               // A_sh(kk+1) ready
    }

    // ---- epilogue: C/D layout col=lane&15 (x), row=(lane>>4)*4+r (c) — R11-verified ----
    const int csub = kq << 2;
    #pragma unroll
    for (int ct = 0; ct < 2; ++ct)
        #pragma unroll
        for (int t6 = 0; t6 < 6; ++t6)
            #pragma unroll
            for (int r = 0; r < 4; ++r)
                out[(((size_t)b * Cn + wid * 32 + ct * 16 + csub + r) * Hn + y) * Wn + t6 * 16 + mrow]
                    = acc[ct][t6][r];
}

extern "C" void kernel_launch(void* const* d_in, const int* in_sizes, int n_in,
                              void* d_out, int out_size, void* d_ws, size_t ws_size,
                              hipStream_t stream)
{
    const float* corr = (const float*)d_in[0];   // [16,81,96,96]
    const float* feat = (const float*)d_in[1];   // [16,256,96,96]
    float* out = (float*)d_out;                  // [16,256,96,96]

    const int grid = Bn * Hn;                    // 1536 blocks: one (b,y) each
    corrT13_kernel<<<grid, NTH, 0, stream>>>(corr, feat, out);
}